// Round 6
// baseline (223.898 us; speedup 1.0000x reference)
//
#include <hip/hip_runtime.h>
#include <hip/hip_bf16.h>
#include <stdint.h>

typedef __bf16 bf16x8 __attribute__((ext_vector_type(8)));
typedef __bf16 bf16x4 __attribute__((ext_vector_type(4)));
typedef float  f32x4  __attribute__((ext_vector_type(4)));

#define D_MODEL 1024
#define NUM_HEADS 16
#define D_K 64
#define BATCH 2
#define SEQ 2048
#define M_TOTAL (BATCH * SEQ)   // 4096

static __device__ __forceinline__ bf16x8 load8(const __bf16* p) {
    return *reinterpret_cast<const bf16x8*>(p);
}

#define MFMA16(a, b, c) __builtin_amdgcn_mfma_f32_16x16x32_bf16((a), (b), (c), 0, 0, 0)

// Async global->LDS, 16B per lane. LDS dest = wave-uniform base + lane*16.
static __device__ __forceinline__ void gload16(const void* g, const void* lds) {
    __builtin_amdgcn_global_load_lds(
        (const __attribute__((address_space(1))) uint32_t*)g,
        (__attribute__((address_space(3))) uint32_t*)lds,
        16, 0, 0);
}

// ---------------------------------------------------------------------------
// One launch: x (2048 blocks) + 4 weight matrices (512 blocks each) fp32->bf16.
// grid = 4096, block = 256, 8 elems/thread.
// ---------------------------------------------------------------------------
__global__ __launch_bounds__(256) void convert_all(
    const float* __restrict__ X,
    const float* __restrict__ Wq, const float* __restrict__ Wk,
    const float* __restrict__ Wv, const float* __restrict__ Wo,
    __bf16* __restrict__ xb,
    __bf16* __restrict__ dq, __bf16* __restrict__ dk,
    __bf16* __restrict__ dv, __bf16* __restrict__ dw)
{
    const float* src; __bf16* dst; size_t idx;
    if (blockIdx.x < 2048) {
        src = X; dst = xb;
        idx = (size_t)blockIdx.x * 256 + threadIdx.x;
    } else {
        const int wb  = blockIdx.x - 2048;
        const int sel = wb >> 9;
        src = (sel == 0) ? Wq : (sel == 1) ? Wk : (sel == 2) ? Wv : Wo;
        dst = (sel == 0) ? dq : (sel == 1) ? dk : (sel == 2) ? dv : dw;
        idx = (size_t)(wb & 511) * 256 + threadIdx.x;
    }
    const f32x4 a = *reinterpret_cast<const f32x4*>(src + idx * 8);
    const f32x4 b = *reinterpret_cast<const f32x4*>(src + idx * 8 + 4);
    bf16x8 r;
#pragma unroll
    for (int e = 0; e < 4; e++) { r[e] = (__bf16)a[e]; r[4 + e] = (__bf16)b[e]; }
    *reinterpret_cast<bf16x8*>(dst + idx * 8) = r;
}

// ---------------------------------------------------------------------------
// QKV GEMM: 128x128 tile, BK=64, swizzled gload16 staging (chunk ^= row&7
// breaks the 8-way frag-read bank conflict of the unswizzled 64B-row layout
// while keeping global_load_lds's contiguous lane*16 dest requirement).
// V output is transposed through LDS scratch and stored as coalesced bf16x8
// rows of V^T (the old scalar 4KB-stride stores were ~32x write-amplified).
// grid = (32, 24), block = 256.
// ---------------------------------------------------------------------------
__global__ __launch_bounds__(256) void qkv_kernel(
    const __bf16* __restrict__ Xb,
    const __bf16* __restrict__ Wqb,
    const __bf16* __restrict__ Wkb,
    const __bf16* __restrict__ Wvb,
    __bf16* __restrict__ Qb,
    __bf16* __restrict__ Kb,
    __bf16* __restrict__ Vtg)
{
    __shared__ alignas(16) char smem[34816];   // As(16K)+Bs(16K); scratch 34K
    __bf16* As = (__bf16*)smem;                // [128][64], chunk-swizzled
    __bf16* Bs = As + 128 * 64;

    const int lane = threadIdx.x & 63;
    const int wid  = threadIdx.x >> 6;
    const int m    = lane & 15;
    const int quad = lane >> 4;
    const int wrow = wid >> 1, wcol = wid & 1;
    const int row0 = blockIdx.x * 128;
    const int col0 = blockIdx.y * 128;
    const int wsel = col0 >> 10;
    const int lcol0 = col0 & 1023;

    const __bf16* W = (wsel == 0) ? Wqb : (wsel == 1) ? Wkb : Wvb;

    f32x4 acc[4][4];
#pragma unroll
    for (int i = 0; i < 4; i++)
#pragma unroll
        for (int j = 0; j < 4; j++) acc[i][j] = (f32x4){0.f, 0.f, 0.f, 0.f};

    for (int k0 = 0; k0 < D_MODEL; k0 += 64) {
#pragma unroll
        for (int i = 0; i < 4; i++) {
            const int slot = wid * 256 + i * 64 + lane;
            const int row  = slot >> 3;
            const int cg   = (slot & 7) ^ (row & 7);
            gload16(Xb + (size_t)(row0 + row) * D_MODEL + k0 + cg * 8,
                    (const char*)As + (size_t)(wid * 256 + i * 64) * 16);
            gload16(W + (size_t)(lcol0 + row) * D_MODEL + k0 + cg * 8,
                    (const char*)Bs + (size_t)(wid * 256 + i * 64) * 16);
        }
        __syncthreads();

        bf16x8 a2[2][4], b2[2][4];
#pragma unroll
        for (int ks = 0; ks < 2; ks++) {
#pragma unroll
            for (int i = 0; i < 4; i++) {
                const int rA = wrow * 64 + i * 16 + m;
                a2[ks][i] = load8(As + rA * 64 + (((ks * 4 + quad) ^ (rA & 7)) * 8));
                const int rB = wcol * 64 + i * 16 + m;
                b2[ks][i] = load8(Bs + rB * 64 + (((ks * 4 + quad) ^ (rB & 7)) * 8));
            }
        }
#pragma unroll
        for (int ks = 0; ks < 2; ks++)
#pragma unroll
            for (int i = 0; i < 4; i++)
#pragma unroll
                for (int j = 0; j < 4; j++)
                    acc[i][j] = MFMA16(a2[ks][i], b2[ks][j], acc[i][j]);
        __syncthreads();
    }

    if (wsel < 2) {
        // Q / K: [bh][s][dk] scalar stores (dk contiguous across m -> OK)
        __bf16* Out = wsel ? Kb : Qb;
#pragma unroll
        for (int i = 0; i < 4; i++) {
#pragma unroll
            for (int r = 0; r < 4; r++) {
                const int R  = row0 + wrow * 64 + i * 16 + quad * 4 + r;
                const int bb = R >> 11;
                const int s  = R & (SEQ - 1);
#pragma unroll
                for (int j = 0; j < 4; j++) {
                    const int e  = lcol0 + wcol * 64 + j * 16 + m;
                    const int h  = e >> 6;
                    const int dk = e & (D_K - 1);
                    Out[((size_t)(bb * NUM_HEADS + h) * SEQ + s) * D_K + dk] =
                        (__bf16)acc[i][j][r];
                }
            }
        }
    } else {
        // V: transpose tile through LDS, store coalesced V^T rows.
        __bf16* Ls = (__bf16*)smem;   // [128][136] (+8 pad, 16B-aligned rows)
#pragma unroll
        for (int i = 0; i < 4; i++)
#pragma unroll
            for (int r = 0; r < 4; r++)
#pragma unroll
                for (int j = 0; j < 4; j++)
                    Ls[(wcol * 64 + j * 16 + m) * 136 +
                       wrow * 64 + i * 16 + quad * 4 + r] = (__bf16)acc[i][j][r];
        __syncthreads();
        const int bb   = row0 >> 11;
        const int sloc = row0 & (SEQ - 1);
#pragma unroll
        for (int i = 0; i < 8; i++) {
            const int c   = i * 256 + threadIdx.x;   // 0..2047
            const int dkl = c >> 4;                  // 0..127 local col
            const int sc  = c & 15;                  // 8-elem s-chunk
            const bf16x8 v = load8(Ls + dkl * 136 + sc * 8);
            const int e  = lcol0 + dkl;
            const int h  = e >> 6;
            const int dk = e & (D_K - 1);
            const int bh = bb * NUM_HEADS + h;
            *reinterpret_cast<bf16x8*>(
                Vtg + ((size_t)bh * D_K + dk) * SEQ + sloc + sc * 8) = v;
        }
    }
}

// ---------------------------------------------------------------------------
// Flash attention, causal, Br=128/Bc=64, S^T layout, swizzled gload16 K/V
// staging. split=1: grid=(32 bh, 32), y>>4 selects key-half (flash-decode);
// stores UNNORMALIZED O + (m,l) partials, merged by merge_kernel.
// split=0: grid=(32,16), single pass, normalizes and writes Cc directly.
// Balanced qx map: co-resident blocks' tile counts sum constant.
// ---------------------------------------------------------------------------
__global__ __launch_bounds__(256) void attn_kernel(
    const __bf16* __restrict__ Qb,
    const __bf16* __restrict__ Kb,
    const __bf16* __restrict__ Vtg,
    __bf16* __restrict__ Cc,
    __bf16* __restrict__ Opart,
    float* __restrict__ Ml,
    int split)
{
    __shared__ alignas(16) __bf16 Ks[64 * 64];     // [key][d], swizzled
    __shared__ alignas(16) __bf16 Vt[64 * 64];     // [d][key], swizzled
    __shared__ alignas(16) __bf16 Pw[4][32][72];   // per-wave P, +8 pad
    __shared__ alignas(16) float  Alf[4][2][16];

    const int lane = threadIdx.x & 63;
    const int wid  = threadIdx.x >> 6;
    const int m    = lane & 15;
    const int quad = lane >> 4;
    const int bh   = blockIdx.x;
    const int b    = bh >> 4;
    const int h    = bh & (NUM_HEADS - 1);

    const int half = split ? (blockIdx.y >> 4) : 0;
    const int y16  = blockIdx.y & 15;
    const int lo   = y16 & 7, hi = y16 >> 3;
    const int qx   = hi ? (15 - lo) : lo;

    const __bf16* Qp = Qb  + (size_t)bh * SEQ * D_K;
    const __bf16* Kp = Kb  + (size_t)bh * SEQ * D_K;
    const __bf16* Vp = Vtg + (size_t)bh * D_K * SEQ;

    const int q0w = qx * 128 + wid * 32;

    bf16x8 qB[2][2];
#pragma unroll
    for (int qg = 0; qg < 2; qg++)
#pragma unroll
        for (int ch = 0; ch < 2; ch++)
            qB[qg][ch] = load8(Qp + (size_t)(q0w + qg * 16 + m) * D_K + ch * 32 + quad * 8);

    f32x4 oacc[2][4];
#pragma unroll
    for (int qg = 0; qg < 2; qg++)
#pragma unroll
        for (int c = 0; c < 4; c++) oacc[qg][c] = (f32x4){0.f, 0.f, 0.f, 0.f};
    float mrow[2] = {-1e30f, -1e30f};
    float lrow[2] = {0.f, 0.f};

    const int tstart = split ? half * (qx + 1) : 0;
    const int tend   = split ? tstart + qx + 1 : 2 * qx + 2;

    for (int t = tstart; t < tend; t++) {
        const int k0 = t * 64;
        // ---- swizzled async staging: K[64][64], V^T[64][64] ----
#pragma unroll
        for (int i = 0; i < 2; i++) {
            const int slot = wid * 128 + i * 64 + lane;
            const int row  = slot >> 3;
            const int cg   = (slot & 7) ^ (row & 7);
            gload16(Kp + (size_t)(k0 + row) * D_K + cg * 8,
                    (const char*)Ks + (size_t)(wid * 128 + i * 64) * 16);
            gload16(Vp + (size_t)row * SEQ + k0 + cg * 8,
                    (const char*)Vt + (size_t)(wid * 128 + i * 64) * 16);
        }
        __syncthreads();

        // ---- S^T = K Q^T: rows = keys, cols = q ----
        float p[2][4][4];
#pragma unroll
        for (int kb = 0; kb < 4; kb++) {
            const int rK = kb * 16 + m;
            const bf16x8 kfA = load8(Ks + rK * 64 + ((quad ^ (m & 7)) * 8));
            const bf16x8 kfB = load8(Ks + rK * 64 + (((quad + 4) ^ (m & 7)) * 8));
#pragma unroll
            for (int qg = 0; qg < 2; qg++) {
                f32x4 st = (f32x4){0.f, 0.f, 0.f, 0.f};
                st = MFMA16(kfA, qB[qg][0], st);
                st = MFMA16(kfB, qB[qg][1], st);
                const int q = q0w + qg * 16 + m;
#pragma unroll
                for (int r = 0; r < 4; r++) {
                    const int key = k0 + kb * 16 + quad * 4 + r;
                    p[qg][kb][r] = (key <= q) ? st[r] * 0.125f : -1e30f;
                }
            }
        }

        // ---- V fragments (before sync2: Vt restaged next tile) ----
        bf16x8 vfA[4], vfB[4];
#pragma unroll
        for (int c = 0; c < 4; c++) {
            const int rV = c * 16 + m;
            vfA[c] = load8(Vt + rV * 64 + ((quad ^ (m & 7)) * 8));
            vfB[c] = load8(Vt + rV * 64 + (((quad + 4) ^ (m & 7)) * 8));
        }

        // ---- online softmax (in-thread tree + 2 shuffles per qg) ----
#pragma unroll
        for (int qg = 0; qg < 2; qg++) {
            float vmax = -1e30f;
#pragma unroll
            for (int kb = 0; kb < 4; kb++)
#pragma unroll
                for (int r = 0; r < 4; r++) vmax = fmaxf(vmax, p[qg][kb][r]);
            vmax = fmaxf(vmax, __shfl_xor(vmax, 16));
            vmax = fmaxf(vmax, __shfl_xor(vmax, 32));
            const float mnew  = fmaxf(mrow[qg], vmax);
            const float alpha = __expf(mrow[qg] - mnew);   // arg <= 0
            float lsum = 0.f;
#pragma unroll
            for (int kb = 0; kb < 4; kb++) {
                bf16x4 pk;
#pragma unroll
                for (int r = 0; r < 4; r++) {
                    // explicit zero for masked: handles fully-masked tiles
                    // (split half-1 rows) where mnew stays -1e30.
                    const float e = (p[qg][kb][r] > -1e29f)
                                  ? __expf(p[qg][kb][r] - mnew) : 0.f;
                    lsum += e;
                    pk[r] = (__bf16)e;
                }
                *reinterpret_cast<bf16x4*>(&Pw[wid][qg * 16 + m][kb * 16 + quad * 4]) = pk;
            }
            lsum += __shfl_xor(lsum, 16);
            lsum += __shfl_xor(lsum, 32);
            lrow[qg] = lrow[qg] * alpha + lsum;
            mrow[qg] = mnew;
            if (quad == 0) Alf[wid][qg][m] = alpha;
        }

        __syncthreads();   // Pw/Alf write->read; Ks/Vt reads done pre-restage

        // ---- rescale O + P·V ----
#pragma unroll
        for (int qg = 0; qg < 2; qg++) {
            const f32x4 af = *reinterpret_cast<const f32x4*>(&Alf[wid][qg][quad * 4]);
#pragma unroll
            for (int c = 0; c < 4; c++)
#pragma unroll
                for (int r = 0; r < 4; r++) oacc[qg][c][r] *= af[r];
            const bf16x8 pfA = load8(&Pw[wid][qg * 16 + m][quad * 8]);
            const bf16x8 pfB = load8(&Pw[wid][qg * 16 + m][32 + quad * 8]);
#pragma unroll
            for (int c = 0; c < 4; c++) {
                oacc[qg][c] = MFMA16(pfA, vfA[c], oacc[qg][c]);
                oacc[qg][c] = MFMA16(pfB, vfB[c], oacc[qg][c]);
            }
        }
    }

    if (split) {
        // ---- store unnormalized partials + (m,l) ----
#pragma unroll
        for (int qg = 0; qg < 2; qg++) {
            if (quad == 0) {
                const size_t rid = (size_t)half * (32 * SEQ) + (size_t)bh * SEQ
                                 + q0w + qg * 16 + m;
                Ml[rid * 2]     = mrow[qg];
                Ml[rid * 2 + 1] = lrow[qg];
            }
#pragma unroll
            for (int r = 0; r < 4; r++) {
                const int s = q0w + qg * 16 + quad * 4 + r;
                const size_t rid = (size_t)half * (32 * SEQ) + (size_t)bh * SEQ + s;
#pragma unroll
                for (int c = 0; c < 4; c++)
                    Opart[rid * D_K + c * 16 + m] = (__bf16)oacc[qg][c][r];
            }
        }
    } else {
        // ---- single-pass: normalize via Alf broadcast, store concat ----
        __syncthreads();
        if (quad == 0) { Alf[wid][0][m] = lrow[0]; Alf[wid][1][m] = lrow[1]; }
        __syncthreads();
#pragma unroll
        for (int qg = 0; qg < 2; qg++) {
            const f32x4 lf = *reinterpret_cast<const f32x4*>(&Alf[wid][qg][quad * 4]);
#pragma unroll
            for (int r = 0; r < 4; r++) {
                const int s = q0w + qg * 16 + quad * 4 + r;
                const float inv = 1.f / lf[r];
#pragma unroll
                for (int c = 0; c < 4; c++) {
                    const size_t o = ((size_t)(b * SEQ + s)) * D_MODEL + h * D_K + c * 16 + m;
                    Cc[o] = (__bf16)(oacc[qg][c][r] * inv);
                }
            }
        }
    }
}

// ---------------------------------------------------------------------------
// Merge the two key-halves: O = (a0*O0 + a1*O1) / (a0*l0 + a1*l1).
// grid = 2048, block = 256 (8 threads per q-row, 8 dims each).
// ---------------------------------------------------------------------------
__global__ __launch_bounds__(256) void merge_kernel(
    const __bf16* __restrict__ Opart,
    const float* __restrict__ Ml,
    __bf16* __restrict__ Cc)
{
    const int rl   = threadIdx.x >> 3;
    const int dseg = (threadIdx.x & 7) * 8;
    const size_t row = (size_t)blockIdx.x * 32 + rl;   // bh*SEQ + s
    const int bh = (int)(row >> 11);
    const int s  = (int)(row & (SEQ - 1));
    const int b  = bh >> 4;
    const int h  = bh & (NUM_HEADS - 1);

    const float m0 = Ml[row * 2],                  l0 = Ml[row * 2 + 1];
    const float m1 = Ml[(32 * (size_t)SEQ + row) * 2], l1 = Ml[(32 * (size_t)SEQ + row) * 2 + 1];
    const float M  = fmaxf(m0, m1);
    const float a0 = __expf(m0 - M);
    const float a1 = __expf(m1 - M);
    const float inv = 1.f / (a0 * l0 + a1 * l1);

    const bf16x8 o0 = load8(Opart + row * D_K + dseg);
    const bf16x8 o1 = load8(Opart + (32 * (size_t)SEQ + row) * D_K + dseg);
    bf16x8 r;
#pragma unroll
    for (int e = 0; e < 8; e++)
        r[e] = (__bf16)((a0 * (float)o0[e] + a1 * (float)o1[e]) * inv);
    *reinterpret_cast<bf16x8*>(
        Cc + ((size_t)(b * SEQ + s)) * D_MODEL + h * D_K + dseg) = r;
}

// ---------------------------------------------------------------------------
// Output projection: Out = Cc * Wo^T + bo (fp32). BK=64, swizzled staging.
// grid = (32, 8), block = 256.
// ---------------------------------------------------------------------------
__global__ __launch_bounds__(256) void oproj_kernel(
    const __bf16* __restrict__ Cc,
    const __bf16* __restrict__ Wob,
    const float* __restrict__ bo,
    float* __restrict__ Out)
{
    __shared__ alignas(16) __bf16 As[128 * 64];
    __shared__ alignas(16) __bf16 Bs[128 * 64];

    const int lane = threadIdx.x & 63;
    const int wid  = threadIdx.x >> 6;
    const int m    = lane & 15;
    const int quad = lane >> 4;
    const int wrow = wid >> 1, wcol = wid & 1;
    const int row0 = blockIdx.x * 128;
    const int col0 = blockIdx.y * 128;

    f32x4 acc[4][4];
#pragma unroll
    for (int i = 0; i < 4; i++)
#pragma unroll
        for (int j = 0; j < 4; j++) acc[i][j] = (f32x4){0.f, 0.f, 0.f, 0.f};

    for (int k0 = 0; k0 < D_MODEL; k0 += 64) {
#pragma unroll
        for (int i = 0; i < 4; i++) {
            const int slot = wid * 256 + i * 64 + lane;
            const int row  = slot >> 3;
            const int cg   = (slot & 7) ^ (row & 7);
            gload16(Cc + (size_t)(row0 + row) * D_MODEL + k0 + cg * 8,
                    (const char*)As + (size_t)(wid * 256 + i * 64) * 16);
            gload16(Wob + (size_t)(col0 + row) * D_MODEL + k0 + cg * 8,
                    (const char*)Bs + (size_t)(wid * 256 + i * 64) * 16);
        }
        __syncthreads();

        bf16x8 a2[2][4], b2[2][4];
#pragma unroll
        for (int ks = 0; ks < 2; ks++) {
#pragma unroll
            for (int i = 0; i < 4; i++) {
                const int rA = wrow * 64 + i * 16 + m;
                a2[ks][i] = load8(As + rA * 64 + (((ks * 4 + quad) ^ (rA & 7)) * 8));
                const int rB = wcol * 64 + i * 16 + m;
                b2[ks][i] = load8(Bs + rB * 64 + (((ks * 4 + quad) ^ (rB & 7)) * 8));
            }
        }
#pragma unroll
        for (int ks = 0; ks < 2; ks++)
#pragma unroll
            for (int i = 0; i < 4; i++)
#pragma unroll
                for (int j = 0; j < 4; j++)
                    acc[i][j] = MFMA16(a2[ks][i], b2[ks][j], acc[i][j]);
        __syncthreads();
    }

#pragma unroll
    for (int i = 0; i < 4; i++) {
#pragma unroll
        for (int r = 0; r < 4; r++) {
            const int R = row0 + wrow * 64 + i * 16 + quad * 4 + r;
#pragma unroll
            for (int j = 0; j < 4; j++) {
                const int E = col0 + wcol * 64 + j * 16 + m;
                Out[(size_t)R * D_MODEL + E] = acc[i][j][r] + bo[E];
            }
        }
    }
}

// ---------------------------------------------------------------------------
extern "C" void kernel_launch(void* const* d_in, const int* in_sizes, int n_in,
                              void* d_out, int out_size, void* d_ws, size_t ws_size,
                              hipStream_t stream) {
    const float* x  = (const float*)d_in[0];
    const float* Wq = (const float*)d_in[1];
    const float* Wk = (const float*)d_in[2];
    const float* Wv = (const float*)d_in[3];
    const float* Wo = (const float*)d_in[4];
    const float* bo = (const float*)d_in[5];
    // d_in[6] = causal mask — recomputed from indices, not read.

    const size_t elems  = (size_t)M_TOTAL * D_MODEL;   // 4194304
    const size_t welems = (size_t)D_MODEL * D_MODEL;   // 1048576
    __bf16* xb  = (__bf16*)d_ws;       // seg0: x (bf16) -> later Cc (aliased)
    __bf16* Qb  = xb + elems;
    __bf16* Kb  = Qb + elems;
    __bf16* Vtg = Kb + elems;          // [32][64][2048]  (V^T)
    __bf16* Wqb = Vtg + elems;
    __bf16* Wkb = Wqb + welems;
    __bf16* Wvb = Wkb + welems;
    __bf16* Wob = Wvb + welems;        // end: 40 MB
    __bf16* Cc  = xb;

    __bf16* Opart = Wob + welems;                         // 16 MB (2x32x2048x64)
    float*  Ml    = (float*)(Opart + 2 * 32 * (size_t)SEQ * D_K);   // 1 MB
    const size_t needS = (4 * elems + 4 * welems) * 2
                       + 2 * 32 * (size_t)SEQ * D_K * 2
                       + 2 * 32 * (size_t)SEQ * 2 * 4;    // ~57 MB

    // 0) all fp32 -> bf16 conversions in one launch
    convert_all<<<dim3(4096), 256, 0, stream>>>(
        x, Wq, Wk, Wv, Wo, xb, Wqb, Wkb, Wvb, Wob);

    // 1) QKV projections
    qkv_kernel<<<dim3(M_TOTAL / 128, 3 * D_MODEL / 128), 256, 0, stream>>>(
        xb, Wqb, Wkb, Wvb, Qb, Kb, Vtg);

    // 2) causal flash attention (+ merge if ws allows the K-split)
    if (ws_size >= needS) {
        attn_kernel<<<dim3(BATCH * NUM_HEADS, 32), 256, 0, stream>>>(
            Qb, Kb, Vtg, Cc, Opart, Ml, 1);
        merge_kernel<<<dim3(32 * SEQ / 32), 256, 0, stream>>>(Opart, Ml, Cc);
    } else {
        attn_kernel<<<dim3(BATCH * NUM_HEADS, 16), 256, 0, stream>>>(
            Qb, Kb, Vtg, Cc, Opart, Ml, 0);
    }

    // 3) output projection + bias -> fp32 out
    oproj_kernel<<<dim3(M_TOTAL / 128, D_MODEL / 128), 256, 0, stream>>>(
        Cc, Wob, bo, (float*)d_out);
}